// Round 12
// baseline (356.360 us; speedup 1.0000x reference)
//
#include <hip/hip_runtime.h>
#include <math.h>

namespace {

constexpr int N = 50000;
constexpr int E = 800000;

typedef __attribute__((ext_vector_type(8))) short short8;   // 8 bf16 (4 VGPRs)
typedef __attribute__((ext_vector_type(4))) float f32x4;    // MFMA accum
typedef __attribute__((ext_vector_type(2))) float f32x2;

// ---------- bf16 helpers (RTNE) ----------

__device__ inline unsigned short f2bf(float f) {
  unsigned int b = __float_as_uint(f);
  unsigned int r = (b + 0x7fffu + ((b >> 16) & 1u)) >> 16;
  return (unsigned short)r;
}
__device__ inline unsigned int pack2(float a, float b) {
  return (unsigned int)f2bf(a) | ((unsigned int)f2bf(b) << 16);
}

// ---------- fp8 e4m3 helpers (HW cvt, gfx950 OCP) ----------

__device__ inline unsigned int pack4_fp8(float a, float b, float c, float d) {
  int w = 0;
  w = __builtin_amdgcn_cvt_pk_fp8_f32(a, b, w, false);
  w = __builtin_amdgcn_cvt_pk_fp8_f32(c, d, w, true);
  return (unsigned int)w;
}
__device__ inline unsigned char f2fp8(float v) {
  return (unsigned char)(__builtin_amdgcn_cvt_pk_fp8_f32(v, v, 0, false) & 0xff);
}

// ---------- CSR build ----------

__global__ void zero_int(int* p, int n) {
  int i = blockIdx.x * blockDim.x + threadIdx.x;
  if (i < n) p[i] = 0;
}

__global__ void count_deg_rank(const int* __restrict__ dst, int* __restrict__ cnt,
                               int* __restrict__ rank, int e) {
  int i = blockIdx.x * blockDim.x + threadIdx.x;
  if (i < e) rank[i] = atomicAdd(&cnt[dst[i]], 1);
}

__global__ void block_sums(const int* __restrict__ cnt, int* __restrict__ bsum, int n) {
  int tid = threadIdx.x;
  int i = blockIdx.x * 256 + tid;
  int v = (i < n) ? cnt[i] : 0;
  for (int off = 32; off > 0; off >>= 1) v += __shfl_down(v, off, 64);
  __shared__ int sred[4];
  if ((tid & 63) == 0) sred[tid >> 6] = v;
  __syncthreads();
  if (tid == 0) bsum[blockIdx.x] = sred[0] + sred[1] + sred[2] + sred[3];
}

__global__ void scan_bsums(int* bsum, int nb) {
  if (threadIdx.x == 0 && blockIdx.x == 0) {
    int run = 0;
    for (int b = 0; b < nb; ++b) { int t = bsum[b]; bsum[b] = run; run += t; }
  }
}

__global__ void scan_chunks(const int* __restrict__ cnt, const int* __restrict__ bsum,
                            int* __restrict__ row_ptr, int n) {
  __shared__ int s[256];
  int tid = threadIdx.x;
  int i = blockIdx.x * 256 + tid;
  int v = (i < n) ? cnt[i] : 0;
  s[tid] = v;
  __syncthreads();
  for (int d = 1; d < 256; d <<= 1) {
    int t = (tid >= d) ? s[tid - d] : 0;
    __syncthreads();
    s[tid] += t;
    __syncthreads();
  }
  if (i < n) {
    int excl = bsum[blockIdx.x] + s[tid] - v;
    row_ptr[i] = excl;
    if (i == n - 1) row_ptr[n] = excl + v;
  }
}

__global__ void compute_dinv(const int* __restrict__ cnt, float* __restrict__ dinv, int n) {
  int i = blockIdx.x * blockDim.x + threadIdx.x;
  if (i < n) dinv[i] = rsqrtf((float)(cnt[i] + 1));
}

// XCD-filtered scatter (see R6).
__global__ __launch_bounds__(256) void scatter_xcd(const int* __restrict__ src,
                                                   const int* __restrict__ dst,
                                                   const int* __restrict__ rank,
                                                   const int* __restrict__ row_ptr,
                                                   int* __restrict__ csr_src) {
  constexpr int RANGE = (N + 7) / 8;  // 6250
  int r = blockIdx.x & 7;
  int lo = r * RANGE;
  int hi = lo + RANGE;
  int nb = gridDim.x >> 3;
  int bi = blockIdx.x >> 3;
  for (int e = bi * 256 + threadIdx.x; e < E; e += nb * 256) {
    int d = dst[e];
    if (d >= lo && d < hi) {
      csr_src[row_ptr[d] + rank[e]] = src[e];
    }
  }
}

// ---------- conversions / weight packing ----------

// condition fp32 [N x 64] -> buf256 bytes 128..191 (fp8, pre-scaled by dinv[i]); bytes 192..255 pad
__global__ void cvt_cond(const float* __restrict__ in, const float* __restrict__ dinv,
                         unsigned char* __restrict__ out, int n) {
  int t = blockIdx.x * blockDim.x + threadIdx.x;
  if (t >= n * 8) return;
  int i = t >> 3, j = t & 7;
  float di = dinv[i];
  const float* s = in + (size_t)i * 64 + j * 8;
  float4 a = *(const float4*)s;
  float4 b = *(const float4*)(s + 4);
  uint2 o;
  o.x = pack4_fp8(di * a.x, di * a.y, di * a.z, di * a.w);
  o.y = pack4_fp8(di * b.x, di * b.y, di * b.z, di * b.w);
  *(uint2*)(out + (size_t)i * 256 + 128 + j * 8) = o;
  // zero the pad so gathers decode benign values
  *(uint2*)(out + (size_t)i * 256 + 192 + j * 8) = make_uint2(0u, 0u);
}

// Pack W[K x 128] into MFMA B-fragment order.
__global__ void pack_w(const float* __restrict__ W1, int s1,
                       const float* __restrict__ W2, int s2, int split,
                       int ksteps, unsigned short* __restrict__ out) {
  int t = blockIdx.x * blockDim.x + threadIdx.x;
  int total = ksteps * 8 * 64;
  if (t >= total) return;
  int ks = t >> 9;
  int ct = (t >> 6) & 7;
  int l = t & 63;
  int k0 = ks * 32 + ((l >> 4) << 3);
  int col = ct * 16 + (l & 15);
  const float* src;
  int c;
  if (col < split) { src = W1 + col; c = s1; }
  else { src = W2 + (col - split); c = s2; }
  unsigned short* o = out + (size_t)t * 8;
#pragma unroll
  for (int i = 0; i < 8; ++i) o[i] = f2bf(src[(size_t)(k0 + i) * c]);
}

__global__ void make_bcat(const float* __restrict__ bm, const float* __restrict__ bl,
                          float* __restrict__ bcat) {
  int j = threadIdx.x;
  if (j < 64) bcat[j] = bm[j];
  else if (j < 128) bcat[j] = bl[j - 64];
}

// ---------- MFMA GEMM: C[n x 128] = A[n x K] @ Wp ----------
// EPI 0: plain; EPI 1: tanh(acc+bias); EPI 2: dscale[row]*acc.
// OUT 0: bf16 store; OUT 1: fp8 store.

template <int K, int EPI, bool F32A, int OUT>
__global__ __launch_bounds__(256) void gemm_mfma(const void* __restrict__ Av, int lda,
                                                 const unsigned short* __restrict__ Wp,
                                                 const float* __restrict__ bias_or_scale,
                                                 void* __restrict__ Cv, int ldc, int n) {
  constexpr int KSTEPS = K / 32;
  int tid = threadIdx.x;
  int w = tid >> 6;
  int l = tid & 63;
  int r0 = blockIdx.x * 128 + w * 32;
  int arow = l & 15;
  int kgrp = l >> 4;

  f32x4 acc[2][8];
#pragma unroll
  for (int m = 0; m < 2; ++m)
#pragma unroll
    for (int ct = 0; ct < 8; ++ct) acc[m][ct] = (f32x4)(0.f);

  int ra0 = min(r0 + arow, n - 1);
  int ra1 = min(r0 + 16 + arow, n - 1);

#pragma unroll 1
  for (int ks = 0; ks < KSTEPS; ++ks) {
    short8 a0, a1;
    if (F32A) {
      const float* p0 = (const float*)Av + (size_t)ra0 * lda + kgrp * 8 + ks * 32;
      const float* p1 = (const float*)Av + (size_t)ra1 * lda + kgrp * 8 + ks * 32;
      float4 x0 = *(const float4*)p0, y0 = *(const float4*)(p0 + 4);
      float4 x1 = *(const float4*)p1, y1 = *(const float4*)(p1 + 4);
      unsigned int u[4];
      u[0] = pack2(x0.x, x0.y); u[1] = pack2(x0.z, x0.w);
      u[2] = pack2(y0.x, y0.y); u[3] = pack2(y0.z, y0.w);
      a0 = *(const short8*)u;
      u[0] = pack2(x1.x, x1.y); u[1] = pack2(x1.z, x1.w);
      u[2] = pack2(y1.x, y1.y); u[3] = pack2(y1.z, y1.w);
      a1 = *(const short8*)u;
    } else {
      a0 = *(const short8*)((const unsigned short*)Av + (size_t)ra0 * lda + kgrp * 8 + ks * 32);
      a1 = *(const short8*)((const unsigned short*)Av + (size_t)ra1 * lda + kgrp * 8 + ks * 32);
    }
    const short8* pb = (const short8*)Wp + (size_t)(ks * 8) * 64 + l;
#pragma unroll
    for (int ct = 0; ct < 8; ++ct) {
      short8 b = pb[ct * 64];
      acc[0][ct] = __builtin_amdgcn_mfma_f32_16x16x32_bf16(a0, b, acc[0][ct], 0, 0, 0);
      acc[1][ct] = __builtin_amdgcn_mfma_f32_16x16x32_bf16(a1, b, acc[1][ct], 0, 0, 0);
    }
  }

  int ccol = l & 15;
  int crow = (l >> 4) * 4;
#pragma unroll
  for (int ct = 0; ct < 8; ++ct) {
    int col = ct * 16 + ccol;
    float bv = (EPI == 1) ? bias_or_scale[col] : 0.f;
#pragma unroll
    for (int m = 0; m < 2; ++m) {
#pragma unroll
      for (int r = 0; r < 4; ++r) {
        int row = r0 + m * 16 + crow + r;
        if (row < n) {
          float v = acc[m][ct][r];
          if (EPI == 1) v = tanhf(v + bv);
          if (EPI == 2) v = v * bias_or_scale[row];
          if (OUT == 0)
            ((unsigned short*)Cv)[(size_t)row * ldc + col] = f2bf(v);
          else
            ((unsigned char*)Cv)[(size_t)row * ldc + col] = f2fp8(v);
        }
      }
    }
  }
}

// ---------- decode macro ----------

#define ACC16_ADD_FP8(ACC, U)                                           \
  {                                                                     \
    f32x2 t0 = __builtin_amdgcn_cvt_pk_f32_fp8((int)U.x, false);        \
    f32x2 t1 = __builtin_amdgcn_cvt_pk_f32_fp8((int)U.x, true);         \
    f32x2 t2 = __builtin_amdgcn_cvt_pk_f32_fp8((int)U.y, false);        \
    f32x2 t3 = __builtin_amdgcn_cvt_pk_f32_fp8((int)U.y, true);         \
    f32x2 t4 = __builtin_amdgcn_cvt_pk_f32_fp8((int)U.z, false);        \
    f32x2 t5 = __builtin_amdgcn_cvt_pk_f32_fp8((int)U.z, true);         \
    f32x2 t6 = __builtin_amdgcn_cvt_pk_f32_fp8((int)U.w, false);        \
    f32x2 t7 = __builtin_amdgcn_cvt_pk_f32_fp8((int)U.w, true);         \
    ACC[0] += t0[0]; ACC[1] += t0[1]; ACC[2] += t1[0]; ACC[3] += t1[1]; \
    ACC[4] += t2[0]; ACC[5] += t2[1]; ACC[6] += t3[0]; ACC[7] += t3[1]; \
    ACC[8] += t4[0]; ACC[9] += t4[1]; ACC[10] += t5[0]; ACC[11] += t5[1]; \
    ACC[12] += t6[0]; ACC[13] += t6[1]; ACC[14] += t7[0]; ACC[15] += t7[1]; \
  }

// ---------- wave-per-row prop over 256B fp8 rows: [uf'(128B) | cond'(64B) | pad] ----------
// One row per wave; 4 lane-groups each gather a different edge (16 lanes x 16B = 256B row).
// Cross-group combine via shfl_xor(16,32); epilogue on group 0.

__global__ __launch_bounds__(256) void prop256(const unsigned char* __restrict__ X,
                                               unsigned short* __restrict__ f2h_out,
                                               unsigned short* __restrict__ pc_out,
                                               const int* __restrict__ row_ptr,
                                               const int* __restrict__ csr_src,
                                               const float* __restrict__ dinv,
                                               const float* __restrict__ b_f2h, int n) {
  int lane = threadIdx.x & 63;
  int wl = lane & 15;   // 16B slot within row
  int g = lane >> 4;    // edge group 0..3
  int i = blockIdx.x * 4 + (threadIdx.x >> 6);
  if (i >= n) return;
  const uint4* X16 = (const uint4*)X;  // 16 uint4 per 256B row
  float di = dinv[i];
  int e0 = row_ptr[i];
  int total = row_ptr[i + 1] - e0 + 1;  // items incl. self
  int itc = (total + 3) >> 2;
  float acc[16], accB[16];
#pragma unroll
  for (int j = 0; j < 16; ++j) { acc[j] = 0.f; accB[j] = 0.f; }
  int it = 0;
  for (; it + 2 <= itc; it += 2) {
    int itemA = it * 4 + g;
    int itemB = itemA + 4;
    bool aA = itemA < total;
    bool aB = itemB < total;
    int sA = i, sB = i;
    if (aA && itemA > 0) sA = csr_src[e0 + itemA - 1];
    if (aB) sB = csr_src[e0 + itemB - 1];
    if (aA) { uint4 u = X16[(size_t)sA * 16 + wl]; ACC16_ADD_FP8(acc, u) }
    if (aB) { uint4 u = X16[(size_t)sB * 16 + wl]; ACC16_ADD_FP8(accB, u) }
  }
  if (it < itc) {
    int item = it * 4 + g;
    bool a = item < total;
    int s = i;
    if (a && item > 0) s = csr_src[e0 + item - 1];
    if (a) { uint4 u = X16[(size_t)s * 16 + wl]; ACC16_ADD_FP8(acc, u) }
  }
#pragma unroll
  for (int j = 0; j < 16; ++j) {
    float v = acc[j] + accB[j];
    v += __shfl_xor(v, 16);
    v += __shfl_xor(v, 32);
    acc[j] = v;
  }
  if (g != 0) return;
  if (wl < 8) {
    float out[16];
#pragma unroll
    for (int j = 0; j < 16; ++j) out[j] = tanhf(fmaf(di, acc[j], b_f2h[wl * 16 + j]));
    unsigned short* yp = f2h_out + (size_t)i * 256 + wl * 16;
    uint4 o0, o1;
    o0.x = pack2(out[0], out[1]); o0.y = pack2(out[2], out[3]);
    o0.z = pack2(out[4], out[5]); o0.w = pack2(out[6], out[7]);
    o1.x = pack2(out[8], out[9]); o1.y = pack2(out[10], out[11]);
    o1.z = pack2(out[12], out[13]); o1.w = pack2(out[14], out[15]);
    *(uint4*)yp = o0;
    *(uint4*)(yp + 8) = o1;
  } else if (wl < 12) {
    unsigned short* yp = pc_out + (size_t)i * 64 + (wl - 8) * 16;
    uint4 o0, o1;
    o0.x = pack2(di * acc[0], di * acc[1]); o0.y = pack2(di * acc[2], di * acc[3]);
    o0.z = pack2(di * acc[4], di * acc[5]); o0.w = pack2(di * acc[6], di * acc[7]);
    o1.x = pack2(di * acc[8], di * acc[9]); o1.y = pack2(di * acc[10], di * acc[11]);
    o1.z = pack2(di * acc[12], di * acc[13]); o1.w = pack2(di * acc[14], di * acc[15]);
    *(uint4*)yp = o0;
    *(uint4*)(yp + 8) = o1;
  }
}

// ---------- wave-per-row 128B fp8 prop: 8 groups x 8 lanes, tanh+bias, bf16 out ----------

__global__ __launch_bounds__(256) void prop128(const unsigned char* __restrict__ X,
                                               unsigned short* __restrict__ Y,
                                               const int* __restrict__ row_ptr,
                                               const int* __restrict__ csr_src,
                                               const float* __restrict__ dinv,
                                               const float* __restrict__ bias, int n) {
  int lane = threadIdx.x & 63;
  int wl = lane & 7;
  int g = lane >> 3;    // 0..7
  int i = blockIdx.x * 4 + (threadIdx.x >> 6);
  if (i >= n) return;
  const uint4* X16 = (const uint4*)X;  // 8 uint4 per 128B row
  float di = dinv[i];
  int e0 = row_ptr[i];
  int total = row_ptr[i + 1] - e0 + 1;
  int itc = (total + 7) >> 3;
  float acc[16], accB[16];
#pragma unroll
  for (int j = 0; j < 16; ++j) { acc[j] = 0.f; accB[j] = 0.f; }
  int it = 0;
  for (; it + 2 <= itc; it += 2) {
    int itemA = it * 8 + g;
    int itemB = itemA + 8;
    bool aA = itemA < total;
    bool aB = itemB < total;
    int sA = i, sB = i;
    if (aA && itemA > 0) sA = csr_src[e0 + itemA - 1];
    if (aB) sB = csr_src[e0 + itemB - 1];
    if (aA) { uint4 u = X16[(size_t)sA * 8 + wl]; ACC16_ADD_FP8(acc, u) }
    if (aB) { uint4 u = X16[(size_t)sB * 8 + wl]; ACC16_ADD_FP8(accB, u) }
  }
  if (it < itc) {
    int item = it * 8 + g;
    bool a = item < total;
    int s = i;
    if (a && item > 0) s = csr_src[e0 + item - 1];
    if (a) { uint4 u = X16[(size_t)s * 8 + wl]; ACC16_ADD_FP8(acc, u) }
  }
#pragma unroll
  for (int j = 0; j < 16; ++j) {
    float v = acc[j] + accB[j];
    v += __shfl_xor(v, 8);
    v += __shfl_xor(v, 16);
    v += __shfl_xor(v, 32);
    acc[j] = v;
  }
  if (g != 0) return;
  float out[16];
#pragma unroll
  for (int j = 0; j < 16; ++j) out[j] = tanhf(fmaf(di, acc[j], bias[wl * 16 + j]));
  unsigned short* yp = Y + (size_t)i * 128 + wl * 16;
  uint4 o0, o1;
  o0.x = pack2(out[0], out[1]); o0.y = pack2(out[2], out[3]);
  o0.z = pack2(out[4], out[5]); o0.w = pack2(out[6], out[7]);
  o1.x = pack2(out[8], out[9]); o1.y = pack2(out[10], out[11]);
  o1.z = pack2(out[12], out[13]); o1.w = pack2(out[14], out[15]);
  *(uint4*)yp = o0;
  *(uint4*)(yp + 8) = o1;
}

// ---------- wave-per-row final prop (fp8 128B rows) + fused reparam epilogue ----------
// Group 0 epilogue: wl 0-3 = mean cols, wl 4-7 = logvar cols; z via row-local shuffle.

__global__ __launch_bounds__(256) void prop_fin(const unsigned char* __restrict__ X,
                                                const int* __restrict__ row_ptr,
                                                const int* __restrict__ csr_src,
                                                const float* __restrict__ dinv,
                                                const float* __restrict__ bcat,
                                                const float* __restrict__ noise,
                                                float* __restrict__ out, int n) {
  int lane = threadIdx.x & 63;
  int wl = lane & 7;
  int g = lane >> 3;
  int i = blockIdx.x * 4 + (threadIdx.x >> 6);
  if (i >= n) return;
  const uint4* X16 = (const uint4*)X;
  float di = dinv[i];
  int e0 = row_ptr[i];
  int total = row_ptr[i + 1] - e0 + 1;
  int itc = (total + 7) >> 3;
  float acc[16], accB[16];
#pragma unroll
  for (int j = 0; j < 16; ++j) { acc[j] = 0.f; accB[j] = 0.f; }
  int it = 0;
  for (; it + 2 <= itc; it += 2) {
    int itemA = it * 8 + g;
    int itemB = itemA + 8;
    bool aA = itemA < total;
    bool aB = itemB < total;
    int sA = i, sB = i;
    if (aA && itemA > 0) sA = csr_src[e0 + itemA - 1];
    if (aB) sB = csr_src[e0 + itemB - 1];
    if (aA) { uint4 u = X16[(size_t)sA * 8 + wl]; ACC16_ADD_FP8(acc, u) }
    if (aB) { uint4 u = X16[(size_t)sB * 8 + wl]; ACC16_ADD_FP8(accB, u) }
  }
  if (it < itc) {
    int item = it * 8 + g;
    bool a = item < total;
    int s = i;
    if (a && item > 0) s = csr_src[e0 + item - 1];
    if (a) { uint4 u = X16[(size_t)s * 8 + wl]; ACC16_ADD_FP8(acc, u) }
  }
#pragma unroll
  for (int j = 0; j < 16; ++j) {
    float v = acc[j] + accB[j];
    v += __shfl_xor(v, 8);
    v += __shfl_xor(v, 16);
    v += __shfl_xor(v, 32);
    acc[j] = v;
  }
  if (g != 0) return;
  // lanes 0-7 active: wl 0-3 mean cols wl*16.., wl 4-7 logvar cols (wl-4)*16..
  float v[16];
#pragma unroll
  for (int j = 0; j < 16; ++j) v[j] = fmaf(di, acc[j], bcat[wl * 16 + j]);
  const float* nz = noise + (size_t)i * 64 + (wl & 3) * 16;
  float tt[16];
#pragma unroll
  for (int j = 0; j < 16; ++j) tt[j] = nz[j] * expf(0.5f * v[j]);
  int srcl = 4 + (wl & 3);
  float z[16];
#pragma unroll
  for (int j = 0; j < 16; ++j) z[j] = v[j] + __shfl(tt[j], srcl);

  size_t n64 = (size_t)n * 64;
  if (wl < 4) {
    float* zp = out + (size_t)i * 64 + wl * 16;
    *(float4*)zp = make_float4(z[0], z[1], z[2], z[3]);
    *(float4*)(zp + 4) = make_float4(z[4], z[5], z[6], z[7]);
    *(float4*)(zp + 8) = make_float4(z[8], z[9], z[10], z[11]);
    *(float4*)(zp + 12) = make_float4(z[12], z[13], z[14], z[15]);
    float* mp = out + n64 + (size_t)i * 64 + wl * 16;
    *(float4*)mp = make_float4(v[0], v[1], v[2], v[3]);
    *(float4*)(mp + 4) = make_float4(v[4], v[5], v[6], v[7]);
    *(float4*)(mp + 8) = make_float4(v[8], v[9], v[10], v[11]);
    *(float4*)(mp + 12) = make_float4(v[12], v[13], v[14], v[15]);
  } else {
    float* lp = out + 2 * n64 + (size_t)i * 64 + (wl - 4) * 16;
    *(float4*)lp = make_float4(v[0], v[1], v[2], v[3]);
    *(float4*)(lp + 4) = make_float4(v[4], v[5], v[6], v[7]);
    *(float4*)(lp + 8) = make_float4(v[8], v[9], v[10], v[11]);
    *(float4*)(lp + 12) = make_float4(v[12], v[13], v[14], v[15]);
  }
}

}  // namespace

extern "C" void kernel_launch(void* const* d_in, const int* in_sizes, int n_in,
                              void* d_out, int out_size, void* d_ws, size_t ws_size,
                              hipStream_t stream) {
  const float* feature   = (const float*)d_in[0];
  const float* condition = (const float*)d_in[1];
  const int*   ei        = (const int*)d_in[2];
  const float* noise     = (const float*)d_in[3];
  const float* W_f2h     = (const float*)d_in[4];
  const float* b_f2h     = (const float*)d_in[5];
  const float* W_c2h     = (const float*)d_in[6];
  const float* b_c2h     = (const float*)d_in[7];
  const float* W_h2h     = (const float*)d_in[8];
  const float* b_h2h     = (const float*)d_in[9];
  const float* W_mean    = (const float*)d_in[10];
  const float* b_mean    = (const float*)d_in[11];
  const float* W_logvar  = (const float*)d_in[12];
  const float* b_logvar  = (const float*)d_in[13];

  const int* src = ei;
  const int* dst = ei + E;

  char* p = (char*)d_ws;
  auto alloc = [&](size_t bytes) {
    char* q = p;
    p += (bytes + 255) & ~(size_t)255;
    return q;
  };
  unsigned char*  buf256 = (unsigned char*)alloc((size_t)N * 256);       // [uf'|cond'|pad] fp8
  unsigned char*  u2buf  = (unsigned char*)alloc((size_t)N * 128);       // u2' fp8
  unsigned char*  vbuf   = (unsigned char*)alloc((size_t)N * 128);       // v' fp8
  unsigned short* catbuf = (unsigned short*)alloc((size_t)N * 256 * 2);  // [f2h | c2h] bf16
  unsigned short* Pcbf   = (unsigned short*)alloc((size_t)N * 64 * 2);
  unsigned short* hbuf   = (unsigned short*)alloc((size_t)N * 128 * 2);  // h bf16
  int*   cnt     = (int*)alloc((size_t)N * 4);
  int*   rank    = (int*)alloc((size_t)E * 4);
  int*   row_ptr = (int*)alloc((size_t)(N + 1) * 4);
  int*   csr_src = (int*)alloc((size_t)E * 4);
  int*   bsum    = (int*)alloc(256 * 4);
  float* dinv    = (float*)alloc((size_t)N * 4);
  unsigned short* Wf2h_p = (unsigned short*)alloc(4 * 512 * 8 * 2);
  unsigned short* Wc2h_p = (unsigned short*)alloc(2 * 512 * 8 * 2);
  unsigned short* Wh2h_p = (unsigned short*)alloc(8 * 512 * 8 * 2);
  unsigned short* Wcat_p = (unsigned short*)alloc(4 * 512 * 8 * 2);
  float* bcat    = (float*)alloc(128 * 4);
  (void)ws_size; (void)in_sizes; (void)n_in; (void)out_size;

  int nb = (N + 255) / 256;

  // CSR build + norm
  zero_int<<<nb, 256, 0, stream>>>(cnt, N);
  count_deg_rank<<<(E + 255) / 256, 256, 0, stream>>>(dst, cnt, rank, E);
  block_sums<<<nb, 256, 0, stream>>>(cnt, bsum, N);
  scan_bsums<<<1, 64, 0, stream>>>(bsum, nb);
  scan_chunks<<<nb, 256, 0, stream>>>(cnt, bsum, row_ptr, N);
  compute_dinv<<<(N + 255) / 256, 256, 0, stream>>>(cnt, dinv, N);
  scatter_xcd<<<1024, 256, 0, stream>>>(src, dst, rank, row_ptr, csr_src);

  // conversions + weight packing
  cvt_cond<<<(N * 8 + 255) / 256, 256, 0, stream>>>(condition, dinv, buf256, N);
  pack_w<<<(4 * 512 + 255) / 256, 256, 0, stream>>>(W_f2h, 128, nullptr, 0, 128, 4, Wf2h_p);
  pack_w<<<(2 * 512 + 255) / 256, 256, 0, stream>>>(W_c2h, 128, nullptr, 0, 128, 2, Wc2h_p);
  pack_w<<<(8 * 512 + 255) / 256, 256, 0, stream>>>(W_h2h, 128, nullptr, 0, 128, 8, Wh2h_p);
  pack_w<<<(4 * 512 + 255) / 256, 256, 0, stream>>>(W_mean, 64, W_logvar, 64, 64, 4, Wcat_p);
  make_bcat<<<1, 128, 0, stream>>>(b_mean, b_logvar, bcat);

  int ggrid = (N + 127) / 128;  // 391
  int pgrid = (N + 3) / 4;      // 12500 (one row per wave, 4 waves per block)

  // L1: uf' = dinv*(feature @ W_f2h) -> fp8 buf256 cols 0-127
  gemm_mfma<128, 2, true, 1><<<ggrid, 256, 0, stream>>>(feature, 128, Wf2h_p, dinv, buf256, 256, N);
  // fused prop over [uf'|cond'] fp8: f2h -> catbuf[:, :128], Pc -> Pcbf
  prop256<<<pgrid, 256, 0, stream>>>(buf256, catbuf, Pcbf, row_ptr, csr_src, dinv, b_f2h, N);
  // c2h = tanh(Pc @ W_c2h + b) -> catbuf[:, 128:256]
  gemm_mfma<64, 1, false, 0><<<ggrid, 256, 0, stream>>>(Pcbf, 64, Wc2h_p, b_c2h, catbuf + 128, 256, N);
  // L2: u2' = dinv*(catbuf @ W_h2h) fp8 ; h = tanh(P(u2)+b) bf16 -> hbuf
  gemm_mfma<256, 2, false, 1><<<ggrid, 256, 0, stream>>>(catbuf, 256, Wh2h_p, dinv, u2buf, 128, N);
  prop128<<<pgrid, 256, 0, stream>>>(u2buf, hbuf, row_ptr, csr_src, dinv, b_h2h, N);
  // L3: v' = dinv*(h @ [W_mean|W_logvar]) fp8 ; out = P(v)+bcat fused with reparam
  gemm_mfma<128, 2, false, 1><<<ggrid, 256, 0, stream>>>(hbuf, 128, Wcat_p, dinv, vbuf, 128, N);
  prop_fin<<<pgrid, 256, 0, stream>>>(vbuf, row_ptr, csr_src, dinv, bcat, noise,
                                      (float*)d_out, N);
}

// Round 13
// 283.698 us; speedup vs baseline: 1.2561x; 1.2561x over previous
//
#include <hip/hip_runtime.h>
#include <math.h>

namespace {

constexpr int N = 50000;
constexpr int E = 800000;

typedef __attribute__((ext_vector_type(8))) short short8;   // 8 bf16 (4 VGPRs)
typedef __attribute__((ext_vector_type(4))) float f32x4;    // MFMA accum
typedef __attribute__((ext_vector_type(2))) float f32x2;

// ---------- bf16 helpers (RTNE) ----------

__device__ inline unsigned short f2bf(float f) {
  unsigned int b = __float_as_uint(f);
  unsigned int r = (b + 0x7fffu + ((b >> 16) & 1u)) >> 16;
  return (unsigned short)r;
}
__device__ inline unsigned int pack2(float a, float b) {
  return (unsigned int)f2bf(a) | ((unsigned int)f2bf(b) << 16);
}

// ---------- fp8 e4m3 helpers (HW cvt, gfx950 OCP) ----------

__device__ inline unsigned int pack4_fp8(float a, float b, float c, float d) {
  int w = 0;
  w = __builtin_amdgcn_cvt_pk_fp8_f32(a, b, w, false);
  w = __builtin_amdgcn_cvt_pk_fp8_f32(c, d, w, true);
  return (unsigned int)w;
}
__device__ inline unsigned char f2fp8(float v) {
  return (unsigned char)(__builtin_amdgcn_cvt_pk_fp8_f32(v, v, 0, false) & 0xff);
}

// ---------- CSR build ----------

__global__ void zero_int(int* p, int n) {
  int i = blockIdx.x * blockDim.x + threadIdx.x;
  if (i < n) p[i] = 0;
}

// XCD-filtered degree count: range-group r = blockIdx&7 only counts its dst range,
// so cnt atomics stay in one XCD's L2 (no cross-XCD line ping-pong).
__global__ __launch_bounds__(256) void count_xcd(const int* __restrict__ dst,
                                                 int* __restrict__ cnt) {
  constexpr int RANGE = (N + 7) / 8;  // 6250
  int r = blockIdx.x & 7;
  int lo = r * RANGE;
  int hi = lo + RANGE;
  int nb = gridDim.x >> 3;
  int bi = blockIdx.x >> 3;
  for (int e = bi * 256 + threadIdx.x; e < E; e += nb * 256) {
    int d = dst[e];
    if (d >= lo && d < hi) atomicAdd(&cnt[d], 1);
  }
}

__global__ void block_sums(const int* __restrict__ cnt, int* __restrict__ bsum, int n) {
  int tid = threadIdx.x;
  int i = blockIdx.x * 256 + tid;
  int v = (i < n) ? cnt[i] : 0;
  for (int off = 32; off > 0; off >>= 1) v += __shfl_down(v, off, 64);
  __shared__ int sred[4];
  if ((tid & 63) == 0) sred[tid >> 6] = v;
  __syncthreads();
  if (tid == 0) bsum[blockIdx.x] = sred[0] + sred[1] + sred[2] + sred[3];
}

// Per-block self-computed prefix over bsum (replaces the serial scan_bsums kernel),
// then intra-block scan -> row_ptr, cursor, dinv in one pass.
__global__ void scan_chunks2(const int* __restrict__ cnt, const int* __restrict__ bsum,
                             int nbk, int* __restrict__ row_ptr, int* __restrict__ cursor,
                             float* __restrict__ dinv, int n) {
  __shared__ int s[256];
  __shared__ int sred[4];
  __shared__ int sprefix;
  int tid = threadIdx.x;
  int pv = (tid < nbk && tid < (int)blockIdx.x) ? bsum[tid] : 0;
  for (int off = 32; off > 0; off >>= 1) pv += __shfl_down(pv, off, 64);
  if ((tid & 63) == 0) sred[tid >> 6] = pv;
  __syncthreads();
  if (tid == 0) sprefix = sred[0] + sred[1] + sred[2] + sred[3];
  int i = blockIdx.x * 256 + tid;
  int v = (i < n) ? cnt[i] : 0;
  s[tid] = v;
  __syncthreads();
  for (int d = 1; d < 256; d <<= 1) {
    int t = (tid >= d) ? s[tid - d] : 0;
    __syncthreads();
    s[tid] += t;
    __syncthreads();
  }
  if (i < n) {
    int excl = sprefix + s[tid] - v;
    row_ptr[i] = excl;
    cursor[i] = excl;
    dinv[i] = rsqrtf((float)(v + 1));
    if (i == n - 1) row_ptr[n] = excl + v;
  }
}

// XCD-filtered scatter with cursor atomics (atomic AND csr write both XCD-local).
__global__ __launch_bounds__(256) void scatter_xcd(const int* __restrict__ src,
                                                   const int* __restrict__ dst,
                                                   int* __restrict__ cursor,
                                                   int* __restrict__ csr_src) {
  constexpr int RANGE = (N + 7) / 8;  // 6250
  int r = blockIdx.x & 7;
  int lo = r * RANGE;
  int hi = lo + RANGE;
  int nb = gridDim.x >> 3;
  int bi = blockIdx.x >> 3;
  for (int e = bi * 256 + threadIdx.x; e < E; e += nb * 256) {
    int d = dst[e];
    if (d >= lo && d < hi) {
      int pos = atomicAdd(&cursor[d], 1);
      csr_src[pos] = src[e];
    }
  }
}

// ---------- conversions / weight packing ----------

// condition fp32 [N x 64] -> buf192 bytes 128..191 (fp8, pre-scaled by dinv[i])
__global__ void cvt_cond(const float* __restrict__ in, const float* __restrict__ dinv,
                         unsigned char* __restrict__ out, int n) {
  int t = blockIdx.x * blockDim.x + threadIdx.x;
  if (t >= n * 8) return;
  int i = t >> 3, j = t & 7;
  float di = dinv[i];
  const float* s = in + (size_t)i * 64 + j * 8;
  float4 a = *(const float4*)s;
  float4 b = *(const float4*)(s + 4);
  uint2 o;
  o.x = pack4_fp8(di * a.x, di * a.y, di * a.z, di * a.w);
  o.y = pack4_fp8(di * b.x, di * b.y, di * b.z, di * b.w);
  *(uint2*)(out + (size_t)i * 192 + 128 + j * 8) = o;
}

// Pack W[K x 128] into MFMA B-fragment order.
__global__ void pack_w(const float* __restrict__ W1, int s1,
                       const float* __restrict__ W2, int s2, int split,
                       int ksteps, unsigned short* __restrict__ out) {
  int t = blockIdx.x * blockDim.x + threadIdx.x;
  int total = ksteps * 8 * 64;
  if (t >= total) return;
  int ks = t >> 9;
  int ct = (t >> 6) & 7;
  int l = t & 63;
  int k0 = ks * 32 + ((l >> 4) << 3);
  int col = ct * 16 + (l & 15);
  const float* src;
  int c;
  if (col < split) { src = W1 + col; c = s1; }
  else { src = W2 + (col - split); c = s2; }
  unsigned short* o = out + (size_t)t * 8;
#pragma unroll
  for (int i = 0; i < 8; ++i) o[i] = f2bf(src[(size_t)(k0 + i) * c]);
}

__global__ void make_bcat(const float* __restrict__ bm, const float* __restrict__ bl,
                          float* __restrict__ bcat) {
  int j = threadIdx.x;
  if (j < 64) bcat[j] = bm[j];
  else if (j < 128) bcat[j] = bl[j - 64];
}

// ---------- MFMA GEMM: C[n x 128] = A[n x K] @ Wp ----------
// EPI 0: plain; EPI 1: tanh(acc+bias); EPI 2: dscale[row]*acc.
// OUT 0: bf16 store; OUT 1: fp8 store.

template <int K, int EPI, bool F32A, int OUT>
__global__ __launch_bounds__(256) void gemm_mfma(const void* __restrict__ Av, int lda,
                                                 const unsigned short* __restrict__ Wp,
                                                 const float* __restrict__ bias_or_scale,
                                                 void* __restrict__ Cv, int ldc, int n) {
  constexpr int KSTEPS = K / 32;
  int tid = threadIdx.x;
  int w = tid >> 6;
  int l = tid & 63;
  int r0 = blockIdx.x * 128 + w * 32;
  int arow = l & 15;
  int kgrp = l >> 4;

  f32x4 acc[2][8];
#pragma unroll
  for (int m = 0; m < 2; ++m)
#pragma unroll
    for (int ct = 0; ct < 8; ++ct) acc[m][ct] = (f32x4)(0.f);

  int ra0 = min(r0 + arow, n - 1);
  int ra1 = min(r0 + 16 + arow, n - 1);

#pragma unroll 1
  for (int ks = 0; ks < KSTEPS; ++ks) {
    short8 a0, a1;
    if (F32A) {
      const float* p0 = (const float*)Av + (size_t)ra0 * lda + kgrp * 8 + ks * 32;
      const float* p1 = (const float*)Av + (size_t)ra1 * lda + kgrp * 8 + ks * 32;
      float4 x0 = *(const float4*)p0, y0 = *(const float4*)(p0 + 4);
      float4 x1 = *(const float4*)p1, y1 = *(const float4*)(p1 + 4);
      unsigned int u[4];
      u[0] = pack2(x0.x, x0.y); u[1] = pack2(x0.z, x0.w);
      u[2] = pack2(y0.x, y0.y); u[3] = pack2(y0.z, y0.w);
      a0 = *(const short8*)u;
      u[0] = pack2(x1.x, x1.y); u[1] = pack2(x1.z, x1.w);
      u[2] = pack2(y1.x, y1.y); u[3] = pack2(y1.z, y1.w);
      a1 = *(const short8*)u;
    } else {
      a0 = *(const short8*)((const unsigned short*)Av + (size_t)ra0 * lda + kgrp * 8 + ks * 32);
      a1 = *(const short8*)((const unsigned short*)Av + (size_t)ra1 * lda + kgrp * 8 + ks * 32);
    }
    const short8* pb = (const short8*)Wp + (size_t)(ks * 8) * 64 + l;
#pragma unroll
    for (int ct = 0; ct < 8; ++ct) {
      short8 b = pb[ct * 64];
      acc[0][ct] = __builtin_amdgcn_mfma_f32_16x16x32_bf16(a0, b, acc[0][ct], 0, 0, 0);
      acc[1][ct] = __builtin_amdgcn_mfma_f32_16x16x32_bf16(a1, b, acc[1][ct], 0, 0, 0);
    }
  }

  int ccol = l & 15;
  int crow = (l >> 4) * 4;
#pragma unroll
  for (int ct = 0; ct < 8; ++ct) {
    int col = ct * 16 + ccol;
    float bv = (EPI == 1) ? bias_or_scale[col] : 0.f;
#pragma unroll
    for (int m = 0; m < 2; ++m) {
#pragma unroll
      for (int r = 0; r < 4; ++r) {
        int row = r0 + m * 16 + crow + r;
        if (row < n) {
          float v = acc[m][ct][r];
          if (EPI == 1) v = tanhf(v + bv);
          if (EPI == 2) v = v * bias_or_scale[row];
          if (OUT == 0)
            ((unsigned short*)Cv)[(size_t)row * ldc + col] = f2bf(v);
          else
            ((unsigned char*)Cv)[(size_t)row * ldc + col] = f2fp8(v);
        }
      }
    }
  }
}

// ---------- decode macro ----------

#define ACC16_ADD_FP8(ACC, U)                                           \
  {                                                                     \
    f32x2 t0 = __builtin_amdgcn_cvt_pk_f32_fp8((int)U.x, false);        \
    f32x2 t1 = __builtin_amdgcn_cvt_pk_f32_fp8((int)U.x, true);         \
    f32x2 t2 = __builtin_amdgcn_cvt_pk_f32_fp8((int)U.y, false);        \
    f32x2 t3 = __builtin_amdgcn_cvt_pk_f32_fp8((int)U.y, true);         \
    f32x2 t4 = __builtin_amdgcn_cvt_pk_f32_fp8((int)U.z, false);        \
    f32x2 t5 = __builtin_amdgcn_cvt_pk_f32_fp8((int)U.z, true);         \
    f32x2 t6 = __builtin_amdgcn_cvt_pk_f32_fp8((int)U.w, false);        \
    f32x2 t7 = __builtin_amdgcn_cvt_pk_f32_fp8((int)U.w, true);         \
    ACC[0] += t0[0]; ACC[1] += t0[1]; ACC[2] += t1[0]; ACC[3] += t1[1]; \
    ACC[4] += t2[0]; ACC[5] += t2[1]; ACC[6] += t3[0]; ACC[7] += t3[1]; \
    ACC[8] += t4[0]; ACC[9] += t4[1]; ACC[10] += t5[0]; ACC[11] += t5[1]; \
    ACC[12] += t6[0]; ACC[13] += t6[1]; ACC[14] += t7[0]; ACC[15] += t7[1]; \
  }

// ---------- fused first-layer prop: fp8 192B rows, 12 lanes x uint4, 5 rows/wave ----------

__global__ __launch_bounds__(256) void prop192(const unsigned char* __restrict__ X,
                                               unsigned short* __restrict__ f2h_out,
                                               unsigned short* __restrict__ pc_out,
                                               const int* __restrict__ row_ptr,
                                               const int* __restrict__ csr_src,
                                               const float* __restrict__ dinv,
                                               const float* __restrict__ b_f2h, int n) {
  int wave = threadIdx.x >> 6;
  int wlane = threadIdx.x & 63;
  int rrow = wlane / 12;          // 0..5 (5 = idle)
  int wl = wlane - rrow * 12;     // 0..11
  if (rrow >= 5) return;
  int i = blockIdx.x * 20 + wave * 5 + rrow;
  if (i >= n) return;
  const uint4* X16 = (const uint4*)X;  // 12 uint4 per 192B row
  float di = dinv[i];
  float acc[16], accB[16];
#pragma unroll
  for (int j = 0; j < 16; ++j) { acc[j] = 0.f; accB[j] = 0.f; }
  {
    uint4 u = X16[(size_t)i * 12 + wl];  // self term
    ACC16_ADD_FP8(acc, u)
  }
  int e0 = row_ptr[i], e1 = row_ptr[i + 1];
  int e = e0;
  for (; e + 2 <= e1; e += 2) {
    int s0 = csr_src[e], s1 = csr_src[e + 1];
    uint4 u0 = X16[(size_t)s0 * 12 + wl];
    uint4 u1 = X16[(size_t)s1 * 12 + wl];
    ACC16_ADD_FP8(acc, u0)
    ACC16_ADD_FP8(accB, u1)
  }
  if (e < e1) {
    int s0 = csr_src[e];
    uint4 u0 = X16[(size_t)s0 * 12 + wl];
    ACC16_ADD_FP8(acc, u0)
  }
#pragma unroll
  for (int j = 0; j < 16; ++j) acc[j] += accB[j];

  if (wl < 8) {
    float out[16];
#pragma unroll
    for (int j = 0; j < 16; ++j) out[j] = tanhf(fmaf(di, acc[j], b_f2h[wl * 16 + j]));
    unsigned short* yp = f2h_out + (size_t)i * 256 + wl * 16;
    uint4 o0, o1;
    o0.x = pack2(out[0], out[1]); o0.y = pack2(out[2], out[3]);
    o0.z = pack2(out[4], out[5]); o0.w = pack2(out[6], out[7]);
    o1.x = pack2(out[8], out[9]); o1.y = pack2(out[10], out[11]);
    o1.z = pack2(out[12], out[13]); o1.w = pack2(out[14], out[15]);
    *(uint4*)yp = o0;
    *(uint4*)(yp + 8) = o1;
  } else {
    unsigned short* yp = pc_out + (size_t)i * 64 + (wl - 8) * 16;
    uint4 o0, o1;
    o0.x = pack2(di * acc[0], di * acc[1]); o0.y = pack2(di * acc[2], di * acc[3]);
    o0.z = pack2(di * acc[4], di * acc[5]); o0.w = pack2(di * acc[6], di * acc[7]);
    o1.x = pack2(di * acc[8], di * acc[9]); o1.y = pack2(di * acc[10], di * acc[11]);
    o1.z = pack2(di * acc[12], di * acc[13]); o1.w = pack2(di * acc[14], di * acc[15]);
    *(uint4*)yp = o0;
    *(uint4*)(yp + 8) = o1;
  }
}

// ---------- 128-col fp8 prop: 8 lanes x uint4, tanh+bias, bf16 out ----------

__global__ __launch_bounds__(256) void prop128(const unsigned char* __restrict__ X,
                                               unsigned short* __restrict__ Y,
                                               const int* __restrict__ row_ptr,
                                               const int* __restrict__ csr_src,
                                               const float* __restrict__ dinv,
                                               const float* __restrict__ bias, int n) {
  int wl = threadIdx.x & 7;
  int rloc = threadIdx.x >> 3;
  int i = blockIdx.x * 32 + rloc;
  if (i >= n) return;
  const uint4* X16 = (const uint4*)X;  // 8 uint4 per 128B row
  float di = dinv[i];
  float acc[16], accB[16];
#pragma unroll
  for (int j = 0; j < 16; ++j) { acc[j] = 0.f; accB[j] = 0.f; }
  {
    uint4 u = X16[(size_t)i * 8 + wl];
    ACC16_ADD_FP8(acc, u)
  }
  int e0 = row_ptr[i], e1 = row_ptr[i + 1];
  int e = e0;
  for (; e + 2 <= e1; e += 2) {
    int s0 = csr_src[e], s1 = csr_src[e + 1];
    uint4 u0 = X16[(size_t)s0 * 8 + wl];
    uint4 u1 = X16[(size_t)s1 * 8 + wl];
    ACC16_ADD_FP8(acc, u0)
    ACC16_ADD_FP8(accB, u1)
  }
  if (e < e1) {
    int s0 = csr_src[e];
    uint4 u0 = X16[(size_t)s0 * 8 + wl];
    ACC16_ADD_FP8(acc, u0)
  }
#pragma unroll
  for (int j = 0; j < 16; ++j) acc[j] += accB[j];

  float out[16];
#pragma unroll
  for (int j = 0; j < 16; ++j) out[j] = tanhf(fmaf(di, acc[j], bias[wl * 16 + j]));
  unsigned short* yp = Y + (size_t)i * 128 + wl * 16;
  uint4 o0, o1;
  o0.x = pack2(out[0], out[1]); o0.y = pack2(out[2], out[3]);
  o0.z = pack2(out[4], out[5]); o0.w = pack2(out[6], out[7]);
  o1.x = pack2(out[8], out[9]); o1.y = pack2(out[10], out[11]);
  o1.z = pack2(out[12], out[13]); o1.w = pack2(out[14], out[15]);
  *(uint4*)yp = o0;
  *(uint4*)(yp + 8) = o1;
}

// ---------- final prop: uniform fp8 128B rows + fused reparam epilogue ----------
// Lane wl holds cols wl*16..+15. Cols 0-63 = mean (lanes 0-3), 64-127 = logvar (lanes 4-7).
// Hot loop identical to prop128 (no divergence); mean/logvar split only in the epilogue.

__global__ __launch_bounds__(256) void prop_fin(const unsigned char* __restrict__ X,
                                                const int* __restrict__ row_ptr,
                                                const int* __restrict__ csr_src,
                                                const float* __restrict__ dinv,
                                                const float* __restrict__ bcat,
                                                const float* __restrict__ noise,
                                                float* __restrict__ out, int n) {
  int wl = threadIdx.x & 7;
  int rloc = threadIdx.x >> 3;
  int i = blockIdx.x * 32 + rloc;
  if (i >= n) return;
  const uint4* X16 = (const uint4*)X;
  float di = dinv[i];
  float acc[16], accB[16];
#pragma unroll
  for (int j = 0; j < 16; ++j) { acc[j] = 0.f; accB[j] = 0.f; }
  {
    uint4 u = X16[(size_t)i * 8 + wl];
    ACC16_ADD_FP8(acc, u)
  }
  int e0 = row_ptr[i], e1 = row_ptr[i + 1];
  int e = e0;
  for (; e + 2 <= e1; e += 2) {
    int s0 = csr_src[e], s1 = csr_src[e + 1];
    uint4 u0 = X16[(size_t)s0 * 8 + wl];
    uint4 u1 = X16[(size_t)s1 * 8 + wl];
    ACC16_ADD_FP8(acc, u0)
    ACC16_ADD_FP8(accB, u1)
  }
  if (e < e1) {
    int s0 = csr_src[e];
    uint4 u0 = X16[(size_t)s0 * 8 + wl];
    ACC16_ADD_FP8(acc, u0)
  }
#pragma unroll
  for (int j = 0; j < 16; ++j) acc[j] += accB[j];

  float v[16];
#pragma unroll
  for (int j = 0; j < 16; ++j) v[j] = fmaf(di, acc[j], bcat[wl * 16 + j]);
  // tt computed uniformly in all lanes; only logvar-lane values are consumed.
  const float* nz = noise + (size_t)i * 64 + (wl & 3) * 16;
  float tt[16];
#pragma unroll
  for (int j = 0; j < 16; ++j) tt[j] = nz[j] * expf(0.5f * v[j]);
  int srcl = ((int)(threadIdx.x & 63) & ~7) + 4 + (wl & 3);
  float z[16];
#pragma unroll
  for (int j = 0; j < 16; ++j) z[j] = v[j] + __shfl(tt[j], srcl);

  size_t n64 = (size_t)n * 64;
  if (wl < 4) {
    float* zp = out + (size_t)i * 64 + wl * 16;
    *(float4*)zp = make_float4(z[0], z[1], z[2], z[3]);
    *(float4*)(zp + 4) = make_float4(z[4], z[5], z[6], z[7]);
    *(float4*)(zp + 8) = make_float4(z[8], z[9], z[10], z[11]);
    *(float4*)(zp + 12) = make_float4(z[12], z[13], z[14], z[15]);
    float* mp = out + n64 + (size_t)i * 64 + wl * 16;
    *(float4*)mp = make_float4(v[0], v[1], v[2], v[3]);
    *(float4*)(mp + 4) = make_float4(v[4], v[5], v[6], v[7]);
    *(float4*)(mp + 8) = make_float4(v[8], v[9], v[10], v[11]);
    *(float4*)(mp + 12) = make_float4(v[12], v[13], v[14], v[15]);
  } else {
    float* lp = out + 2 * n64 + (size_t)i * 64 + (wl - 4) * 16;
    *(float4*)lp = make_float4(v[0], v[1], v[2], v[3]);
    *(float4*)(lp + 4) = make_float4(v[4], v[5], v[6], v[7]);
    *(float4*)(lp + 8) = make_float4(v[8], v[9], v[10], v[11]);
    *(float4*)(lp + 12) = make_float4(v[12], v[13], v[14], v[15]);
  }
}

}  // namespace

extern "C" void kernel_launch(void* const* d_in, const int* in_sizes, int n_in,
                              void* d_out, int out_size, void* d_ws, size_t ws_size,
                              hipStream_t stream) {
  const float* feature   = (const float*)d_in[0];
  const float* condition = (const float*)d_in[1];
  const int*   ei        = (const int*)d_in[2];
  const float* noise     = (const float*)d_in[3];
  const float* W_f2h     = (const float*)d_in[4];
  const float* b_f2h     = (const float*)d_in[5];
  const float* W_c2h     = (const float*)d_in[6];
  const float* b_c2h     = (const float*)d_in[7];
  const float* W_h2h     = (const float*)d_in[8];
  const float* b_h2h     = (const float*)d_in[9];
  const float* W_mean    = (const float*)d_in[10];
  const float* b_mean    = (const float*)d_in[11];
  const float* W_logvar  = (const float*)d_in[12];
  const float* b_logvar  = (const float*)d_in[13];

  const int* src = ei;
  const int* dst = ei + E;

  char* p = (char*)d_ws;
  auto alloc = [&](size_t bytes) {
    char* q = p;
    p += (bytes + 255) & ~(size_t)255;
    return q;
  };
  unsigned char*  buf192 = (unsigned char*)alloc((size_t)N * 192);       // [uf'|cond'] fp8
  unsigned char*  u2buf  = (unsigned char*)alloc((size_t)N * 128);       // u2' fp8
  unsigned char*  vbuf   = (unsigned char*)alloc((size_t)N * 128);       // v' fp8
  unsigned short* catbuf = (unsigned short*)alloc((size_t)N * 256 * 2);  // [f2h | c2h] bf16
  unsigned short* Pcbf   = (unsigned short*)alloc((size_t)N * 64 * 2);
  unsigned short* hbuf   = (unsigned short*)alloc((size_t)N * 128 * 2);  // h bf16
  int*   cnt     = (int*)alloc((size_t)N * 4);
  int*   cursor  = (int*)alloc((size_t)N * 4);
  int*   row_ptr = (int*)alloc((size_t)(N + 1) * 4);
  int*   csr_src = (int*)alloc((size_t)E * 4);
  int*   bsum    = (int*)alloc(256 * 4);
  float* dinv    = (float*)alloc((size_t)N * 4);
  unsigned short* Wf2h_p = (unsigned short*)alloc(4 * 512 * 8 * 2);
  unsigned short* Wc2h_p = (unsigned short*)alloc(2 * 512 * 8 * 2);
  unsigned short* Wh2h_p = (unsigned short*)alloc(8 * 512 * 8 * 2);
  unsigned short* Wcat_p = (unsigned short*)alloc(4 * 512 * 8 * 2);
  float* bcat    = (float*)alloc(128 * 4);
  (void)ws_size; (void)in_sizes; (void)n_in; (void)out_size;

  int nb = (N + 255) / 256;  // 196

  // CSR build + norm (XCD-local atomics; no serial scan kernel)
  zero_int<<<nb, 256, 0, stream>>>(cnt, N);
  count_xcd<<<1024, 256, 0, stream>>>(dst, cnt);
  block_sums<<<nb, 256, 0, stream>>>(cnt, bsum, N);
  scan_chunks2<<<nb, 256, 0, stream>>>(cnt, bsum, nb, row_ptr, cursor, dinv, N);
  scatter_xcd<<<1024, 256, 0, stream>>>(src, dst, cursor, csr_src);

  // conversions + weight packing
  cvt_cond<<<(N * 8 + 255) / 256, 256, 0, stream>>>(condition, dinv, buf192, N);
  pack_w<<<(4 * 512 + 255) / 256, 256, 0, stream>>>(W_f2h, 128, nullptr, 0, 128, 4, Wf2h_p);
  pack_w<<<(2 * 512 + 255) / 256, 256, 0, stream>>>(W_c2h, 128, nullptr, 0, 128, 2, Wc2h_p);
  pack_w<<<(8 * 512 + 255) / 256, 256, 0, stream>>>(W_h2h, 128, nullptr, 0, 128, 8, Wh2h_p);
  pack_w<<<(4 * 512 + 255) / 256, 256, 0, stream>>>(W_mean, 64, W_logvar, 64, 64, 4, Wcat_p);
  make_bcat<<<1, 128, 0, stream>>>(b_mean, b_logvar, bcat);

  int ggrid = (N + 127) / 128;  // 391

  // L1: uf' = dinv*(feature @ W_f2h) -> fp8 buf192 cols 0-127
  gemm_mfma<128, 2, true, 1><<<ggrid, 256, 0, stream>>>(feature, 128, Wf2h_p, dinv, buf192, 192, N);
  // fused prop over [uf'|cond'] fp8: f2h -> catbuf[:, :128], Pc -> Pcbf
  prop192<<<(N + 19) / 20, 256, 0, stream>>>(buf192, catbuf, Pcbf, row_ptr, csr_src, dinv, b_f2h, N);
  // c2h = tanh(Pc @ W_c2h + b) -> catbuf[:, 128:256]
  gemm_mfma<64, 1, false, 0><<<ggrid, 256, 0, stream>>>(Pcbf, 64, Wc2h_p, b_c2h, catbuf + 128, 256, N);
  // L2: u2' = dinv*(catbuf @ W_h2h) fp8 ; h = tanh(P(u2)+b) bf16 -> hbuf
  gemm_mfma<256, 2, false, 1><<<ggrid, 256, 0, stream>>>(catbuf, 256, Wh2h_p, dinv, u2buf, 128, N);
  prop128<<<(N + 31) / 32, 256, 0, stream>>>(u2buf, hbuf, row_ptr, csr_src, dinv, b_h2h, N);
  // L3: v' = dinv*(h @ [W_mean|W_logvar]) fp8 ; out = P(v)+bcat fused with reparam
  gemm_mfma<128, 2, false, 1><<<ggrid, 256, 0, stream>>>(hbuf, 128, Wcat_p, dinv, vbuf, 128, N);
  prop_fin<<<(N + 31) / 32, 256, 0, stream>>>(vbuf, row_ptr, csr_src, dinv, bcat, noise,
                                              (float*)d_out, N);
}

// Round 14
// 269.625 us; speedup vs baseline: 1.3217x; 1.0522x over previous
//
#include <hip/hip_runtime.h>
#include <math.h>

namespace {

constexpr int N = 50000;
constexpr int E = 800000;

typedef __attribute__((ext_vector_type(8))) short short8;   // 8 bf16 (4 VGPRs)
typedef __attribute__((ext_vector_type(4))) float f32x4;    // MFMA accum
typedef __attribute__((ext_vector_type(2))) float f32x2;

// ---------- bf16 helpers (RTNE) ----------

__device__ inline unsigned short f2bf(float f) {
  unsigned int b = __float_as_uint(f);
  unsigned int r = (b + 0x7fffu + ((b >> 16) & 1u)) >> 16;
  return (unsigned short)r;
}
__device__ inline unsigned int pack2(float a, float b) {
  return (unsigned int)f2bf(a) | ((unsigned int)f2bf(b) << 16);
}

// ---------- fp8 e4m3 helpers (HW cvt, gfx950 OCP) ----------

__device__ inline unsigned int pack4_fp8(float a, float b, float c, float d) {
  int w = 0;
  w = __builtin_amdgcn_cvt_pk_fp8_f32(a, b, w, false);
  w = __builtin_amdgcn_cvt_pk_fp8_f32(c, d, w, true);
  return (unsigned int)w;
}
__device__ inline unsigned char f2fp8(float v) {
  return (unsigned char)(__builtin_amdgcn_cvt_pk_fp8_f32(v, v, 0, false) & 0xff);
}

// ---------- CSR build ----------

__global__ void zero_int(int* p, int n) {
  int i = blockIdx.x * blockDim.x + threadIdx.x;
  if (i < n) p[i] = 0;
}

// XCD-filtered degree count (atomics stay in one XCD's L2).
__global__ __launch_bounds__(256) void count_xcd(const int* __restrict__ dst,
                                                 int* __restrict__ cnt) {
  constexpr int RANGE = (N + 7) / 8;  // 6250
  int r = blockIdx.x & 7;
  int lo = r * RANGE;
  int hi = lo + RANGE;
  int nb = gridDim.x >> 3;
  int bi = blockIdx.x >> 3;
  for (int e = bi * 256 + threadIdx.x; e < E; e += nb * 256) {
    int d = dst[e];
    if (d >= lo && d < hi) atomicAdd(&cnt[d], 1);
  }
}

__global__ void block_sums(const int* __restrict__ cnt, int* __restrict__ bsum, int n) {
  int tid = threadIdx.x;
  int i = blockIdx.x * 256 + tid;
  int v = (i < n) ? cnt[i] : 0;
  for (int off = 32; off > 0; off >>= 1) v += __shfl_down(v, off, 64);
  __shared__ int sred[4];
  if ((tid & 63) == 0) sred[tid >> 6] = v;
  __syncthreads();
  if (tid == 0) bsum[blockIdx.x] = sred[0] + sred[1] + sred[2] + sred[3];
}

// Per-block self-computed prefix + intra-block scan -> row_ptr, cursor, dinv.
__global__ void scan_chunks2(const int* __restrict__ cnt, const int* __restrict__ bsum,
                             int nbk, int* __restrict__ row_ptr, int* __restrict__ cursor,
                             float* __restrict__ dinv, int n) {
  __shared__ int s[256];
  __shared__ int sred[4];
  __shared__ int sprefix;
  int tid = threadIdx.x;
  int pv = (tid < nbk && tid < (int)blockIdx.x) ? bsum[tid] : 0;
  for (int off = 32; off > 0; off >>= 1) pv += __shfl_down(pv, off, 64);
  if ((tid & 63) == 0) sred[tid >> 6] = pv;
  __syncthreads();
  if (tid == 0) sprefix = sred[0] + sred[1] + sred[2] + sred[3];
  int i = blockIdx.x * 256 + tid;
  int v = (i < n) ? cnt[i] : 0;
  s[tid] = v;
  __syncthreads();
  for (int d = 1; d < 256; d <<= 1) {
    int t = (tid >= d) ? s[tid - d] : 0;
    __syncthreads();
    s[tid] += t;
    __syncthreads();
  }
  if (i < n) {
    int excl = sprefix + s[tid] - v;
    row_ptr[i] = excl;
    cursor[i] = excl;
    dinv[i] = rsqrtf((float)(v + 1));
    if (i == n - 1) row_ptr[n] = excl + v;
  }
}

// XCD-filtered scatter with cursor atomics.
__global__ __launch_bounds__(256) void scatter_xcd(const int* __restrict__ src,
                                                   const int* __restrict__ dst,
                                                   int* __restrict__ cursor,
                                                   int* __restrict__ csr_src) {
  constexpr int RANGE = (N + 7) / 8;  // 6250
  int r = blockIdx.x & 7;
  int lo = r * RANGE;
  int hi = lo + RANGE;
  int nb = gridDim.x >> 3;
  int bi = blockIdx.x >> 3;
  for (int e = bi * 256 + threadIdx.x; e < E; e += nb * 256) {
    int d = dst[e];
    if (d >= lo && d < hi) {
      int pos = atomicAdd(&cursor[d], 1);
      csr_src[pos] = src[e];
    }
  }
}

// ---------- conversions / weight packing ----------

__global__ void cvt_cond(const float* __restrict__ in, const float* __restrict__ dinv,
                         unsigned char* __restrict__ out, int n) {
  int t = blockIdx.x * blockDim.x + threadIdx.x;
  if (t >= n * 8) return;
  int i = t >> 3, j = t & 7;
  float di = dinv[i];
  const float* s = in + (size_t)i * 64 + j * 8;
  float4 a = *(const float4*)s;
  float4 b = *(const float4*)(s + 4);
  uint2 o;
  o.x = pack4_fp8(di * a.x, di * a.y, di * a.z, di * a.w);
  o.y = pack4_fp8(di * b.x, di * b.y, di * b.z, di * b.w);
  *(uint2*)(out + (size_t)i * 192 + 128 + j * 8) = o;
}

__global__ void pack_w(const float* __restrict__ W1, int s1,
                       const float* __restrict__ W2, int s2, int split,
                       int ksteps, unsigned short* __restrict__ out) {
  int t = blockIdx.x * blockDim.x + threadIdx.x;
  int total = ksteps * 8 * 64;
  if (t >= total) return;
  int ks = t >> 9;
  int ct = (t >> 6) & 7;
  int l = t & 63;
  int k0 = ks * 32 + ((l >> 4) << 3);
  int col = ct * 16 + (l & 15);
  const float* src;
  int c;
  if (col < split) { src = W1 + col; c = s1; }
  else { src = W2 + (col - split); c = s2; }
  unsigned short* o = out + (size_t)t * 8;
#pragma unroll
  for (int i = 0; i < 8; ++i) o[i] = f2bf(src[(size_t)(k0 + i) * c]);
}

__global__ void make_bcat(const float* __restrict__ bm, const float* __restrict__ bl,
                          float* __restrict__ bcat) {
  int j = threadIdx.x;
  if (j < 64) bcat[j] = bm[j];
  else if (j < 128) bcat[j] = bl[j - 64];
}

// ---------- MFMA GEMM: C[n x 128] = A[n x K] @ Wp ----------

template <int K, int EPI, bool F32A, int OUT>
__global__ __launch_bounds__(256) void gemm_mfma(const void* __restrict__ Av, int lda,
                                                 const unsigned short* __restrict__ Wp,
                                                 const float* __restrict__ bias_or_scale,
                                                 void* __restrict__ Cv, int ldc, int n) {
  constexpr int KSTEPS = K / 32;
  int tid = threadIdx.x;
  int w = tid >> 6;
  int l = tid & 63;
  int r0 = blockIdx.x * 128 + w * 32;
  int arow = l & 15;
  int kgrp = l >> 4;

  f32x4 acc[2][8];
#pragma unroll
  for (int m = 0; m < 2; ++m)
#pragma unroll
    for (int ct = 0; ct < 8; ++ct) acc[m][ct] = (f32x4)(0.f);

  int ra0 = min(r0 + arow, n - 1);
  int ra1 = min(r0 + 16 + arow, n - 1);

#pragma unroll 1
  for (int ks = 0; ks < KSTEPS; ++ks) {
    short8 a0, a1;
    if (F32A) {
      const float* p0 = (const float*)Av + (size_t)ra0 * lda + kgrp * 8 + ks * 32;
      const float* p1 = (const float*)Av + (size_t)ra1 * lda + kgrp * 8 + ks * 32;
      float4 x0 = *(const float4*)p0, y0 = *(const float4*)(p0 + 4);
      float4 x1 = *(const float4*)p1, y1 = *(const float4*)(p1 + 4);
      unsigned int u[4];
      u[0] = pack2(x0.x, x0.y); u[1] = pack2(x0.z, x0.w);
      u[2] = pack2(y0.x, y0.y); u[3] = pack2(y0.z, y0.w);
      a0 = *(const short8*)u;
      u[0] = pack2(x1.x, x1.y); u[1] = pack2(x1.z, x1.w);
      u[2] = pack2(y1.x, y1.y); u[3] = pack2(y1.z, y1.w);
      a1 = *(const short8*)u;
    } else {
      a0 = *(const short8*)((const unsigned short*)Av + (size_t)ra0 * lda + kgrp * 8 + ks * 32);
      a1 = *(const short8*)((const unsigned short*)Av + (size_t)ra1 * lda + kgrp * 8 + ks * 32);
    }
    const short8* pb = (const short8*)Wp + (size_t)(ks * 8) * 64 + l;
#pragma unroll
    for (int ct = 0; ct < 8; ++ct) {
      short8 b = pb[ct * 64];
      acc[0][ct] = __builtin_amdgcn_mfma_f32_16x16x32_bf16(a0, b, acc[0][ct], 0, 0, 0);
      acc[1][ct] = __builtin_amdgcn_mfma_f32_16x16x32_bf16(a1, b, acc[1][ct], 0, 0, 0);
    }
  }

  int ccol = l & 15;
  int crow = (l >> 4) * 4;
#pragma unroll
  for (int ct = 0; ct < 8; ++ct) {
    int col = ct * 16 + ccol;
    float bv = (EPI == 1) ? bias_or_scale[col] : 0.f;
#pragma unroll
    for (int m = 0; m < 2; ++m) {
#pragma unroll
      for (int r = 0; r < 4; ++r) {
        int row = r0 + m * 16 + crow + r;
        if (row < n) {
          float v = acc[m][ct][r];
          if (EPI == 1) v = tanhf(v + bv);
          if (EPI == 2) v = v * bias_or_scale[row];
          if (OUT == 0)
            ((unsigned short*)Cv)[(size_t)row * ldc + col] = f2bf(v);
          else
            ((unsigned char*)Cv)[(size_t)row * ldc + col] = f2fp8(v);
        }
      }
    }
  }
}

// ---------- decode macro ----------

#define ACC16_ADD_FP8(ACC, U)                                           \
  {                                                                     \
    f32x2 t0 = __builtin_amdgcn_cvt_pk_f32_fp8((int)U.x, false);        \
    f32x2 t1 = __builtin_amdgcn_cvt_pk_f32_fp8((int)U.x, true);         \
    f32x2 t2 = __builtin_amdgcn_cvt_pk_f32_fp8((int)U.y, false);        \
    f32x2 t3 = __builtin_amdgcn_cvt_pk_f32_fp8((int)U.y, true);         \
    f32x2 t4 = __builtin_amdgcn_cvt_pk_f32_fp8((int)U.z, false);        \
    f32x2 t5 = __builtin_amdgcn_cvt_pk_f32_fp8((int)U.z, true);         \
    f32x2 t6 = __builtin_amdgcn_cvt_pk_f32_fp8((int)U.w, false);        \
    f32x2 t7 = __builtin_amdgcn_cvt_pk_f32_fp8((int)U.w, true);         \
    ACC[0] += t0[0]; ACC[1] += t0[1]; ACC[2] += t1[0]; ACC[3] += t1[1]; \
    ACC[4] += t2[0]; ACC[5] += t2[1]; ACC[6] += t3[0]; ACC[7] += t3[1]; \
    ACC[8] += t4[0]; ACC[9] += t4[1]; ACC[10] += t5[0]; ACC[11] += t5[1]; \
    ACC[12] += t6[0]; ACC[13] += t6[1]; ACC[14] += t7[0]; ACC[15] += t7[1]; \
  }

// Index-prefetch edge walk: per-chunk coalesced index load (LANES indices/chunk),
// consumed via register shuffle -> gathers never wait behind index loads.
// Double-buffered (2 chunks of gathers in flight). csr_src is over-read by up to
// 2 chunks past e1 (allocation padded; values unused due to t<deg guards).
#define EDGE_WALK_PIPE(LANES, ROWSTRIDE)                                \
  int deg = e1 - e0;                                                    \
  int idxA = csr_src[e0 + wl];                                          \
  int idxB = csr_src[e0 + LANES + wl];                                  \
  int cnext = e0 + 2 * LANES;                                           \
  int t = 0;                                                            \
  while (t < deg) {                                                     \
    int idxN = csr_src[cnext + wl];                                     \
    _Pragma("unroll")                                                   \
    for (int k = 0; k < LANES; ++k) {                                   \
      if (t + k < deg) {                                                \
        int s = __shfl(idxA, rowbase + k);                              \
        uint4 u = X16[(size_t)s * ROWSTRIDE + wl];                      \
        ACC16_ADD_FP8(acc, u)                                           \
      }                                                                 \
    }                                                                   \
    idxA = idxB; idxB = idxN;                                           \
    cnext += LANES; t += LANES;                                         \
  }

// ---------- fused first-layer prop: fp8 192B rows, 12 lanes x uint4, 5 rows/wave ----------

__global__ __launch_bounds__(256) void prop192(const unsigned char* __restrict__ X,
                                               unsigned short* __restrict__ f2h_out,
                                               unsigned short* __restrict__ pc_out,
                                               const int* __restrict__ row_ptr,
                                               const int* __restrict__ csr_src,
                                               const float* __restrict__ dinv,
                                               const float* __restrict__ b_f2h, int n) {
  int wave = threadIdx.x >> 6;
  int wlane = threadIdx.x & 63;
  int rrow = wlane / 12;          // 0..5 (5 = idle)
  int wl = wlane - rrow * 12;     // 0..11
  if (rrow >= 5) return;
  int rowbase = rrow * 12;
  int i = blockIdx.x * 20 + wave * 5 + rrow;
  if (i >= n) return;
  const uint4* X16 = (const uint4*)X;  // 12 uint4 per 192B row
  float di = dinv[i];
  float acc[16];
#pragma unroll
  for (int j = 0; j < 16; ++j) acc[j] = 0.f;
  {
    uint4 u = X16[(size_t)i * 12 + wl];  // self term
    ACC16_ADD_FP8(acc, u)
  }
  int e0 = row_ptr[i], e1 = row_ptr[i + 1];
  EDGE_WALK_PIPE(12, 12)

  if (wl < 8) {
    float out[16];
#pragma unroll
    for (int j = 0; j < 16; ++j) out[j] = tanhf(fmaf(di, acc[j], b_f2h[wl * 16 + j]));
    unsigned short* yp = f2h_out + (size_t)i * 256 + wl * 16;
    uint4 o0, o1;
    o0.x = pack2(out[0], out[1]); o0.y = pack2(out[2], out[3]);
    o0.z = pack2(out[4], out[5]); o0.w = pack2(out[6], out[7]);
    o1.x = pack2(out[8], out[9]); o1.y = pack2(out[10], out[11]);
    o1.z = pack2(out[12], out[13]); o1.w = pack2(out[14], out[15]);
    *(uint4*)yp = o0;
    *(uint4*)(yp + 8) = o1;
  } else {
    unsigned short* yp = pc_out + (size_t)i * 64 + (wl - 8) * 16;
    uint4 o0, o1;
    o0.x = pack2(di * acc[0], di * acc[1]); o0.y = pack2(di * acc[2], di * acc[3]);
    o0.z = pack2(di * acc[4], di * acc[5]); o0.w = pack2(di * acc[6], di * acc[7]);
    o1.x = pack2(di * acc[8], di * acc[9]); o1.y = pack2(di * acc[10], di * acc[11]);
    o1.z = pack2(di * acc[12], di * acc[13]); o1.w = pack2(di * acc[14], di * acc[15]);
    *(uint4*)yp = o0;
    *(uint4*)(yp + 8) = o1;
  }
}

// ---------- 128-col fp8 prop: 8 lanes x uint4, tanh+bias, bf16 out ----------

__global__ __launch_bounds__(256) void prop128(const unsigned char* __restrict__ X,
                                               unsigned short* __restrict__ Y,
                                               const int* __restrict__ row_ptr,
                                               const int* __restrict__ csr_src,
                                               const float* __restrict__ dinv,
                                               const float* __restrict__ bias, int n) {
  int wl = threadIdx.x & 7;
  int rloc = threadIdx.x >> 3;
  int rowbase = (threadIdx.x & 63) & ~7;
  int i = blockIdx.x * 32 + rloc;
  if (i >= n) return;
  const uint4* X16 = (const uint4*)X;  // 8 uint4 per 128B row
  float di = dinv[i];
  float acc[16];
#pragma unroll
  for (int j = 0; j < 16; ++j) acc[j] = 0.f;
  {
    uint4 u = X16[(size_t)i * 8 + wl];
    ACC16_ADD_FP8(acc, u)
  }
  int e0 = row_ptr[i], e1 = row_ptr[i + 1];
  EDGE_WALK_PIPE(8, 8)

  float out[16];
#pragma unroll
  for (int j = 0; j < 16; ++j) out[j] = tanhf(fmaf(di, acc[j], bias[wl * 16 + j]));
  unsigned short* yp = Y + (size_t)i * 128 + wl * 16;
  uint4 o0, o1;
  o0.x = pack2(out[0], out[1]); o0.y = pack2(out[2], out[3]);
  o0.z = pack2(out[4], out[5]); o0.w = pack2(out[6], out[7]);
  o1.x = pack2(out[8], out[9]); o1.y = pack2(out[10], out[11]);
  o1.z = pack2(out[12], out[13]); o1.w = pack2(out[14], out[15]);
  *(uint4*)yp = o0;
  *(uint4*)(yp + 8) = o1;
}

// ---------- final prop: uniform fp8 128B rows + fused reparam epilogue ----------

__global__ __launch_bounds__(256) void prop_fin(const unsigned char* __restrict__ X,
                                                const int* __restrict__ row_ptr,
                                                const int* __restrict__ csr_src,
                                                const float* __restrict__ dinv,
                                                const float* __restrict__ bcat,
                                                const float* __restrict__ noise,
                                                float* __restrict__ out, int n) {
  int wl = threadIdx.x & 7;
  int rloc = threadIdx.x >> 3;
  int rowbase = (threadIdx.x & 63) & ~7;
  int i = blockIdx.x * 32 + rloc;
  if (i >= n) return;
  const uint4* X16 = (const uint4*)X;
  float di = dinv[i];
  float acc[16];
#pragma unroll
  for (int j = 0; j < 16; ++j) acc[j] = 0.f;
  {
    uint4 u = X16[(size_t)i * 8 + wl];
    ACC16_ADD_FP8(acc, u)
  }
  int e0 = row_ptr[i], e1 = row_ptr[i + 1];
  EDGE_WALK_PIPE(8, 8)

  float v[16];
#pragma unroll
  for (int j = 0; j < 16; ++j) v[j] = fmaf(di, acc[j], bcat[wl * 16 + j]);
  // tt computed uniformly in all lanes; only logvar-lane values are consumed.
  const float* nz = noise + (size_t)i * 64 + (wl & 3) * 16;
  float tt[16];
#pragma unroll
  for (int j = 0; j < 16; ++j) tt[j] = nz[j] * expf(0.5f * v[j]);
  int srcl = rowbase + 4 + (wl & 3);
  float z[16];
#pragma unroll
  for (int j = 0; j < 16; ++j) z[j] = v[j] + __shfl(tt[j], srcl);

  size_t n64 = (size_t)n * 64;
  if (wl < 4) {
    float* zp = out + (size_t)i * 64 + wl * 16;
    *(float4*)zp = make_float4(z[0], z[1], z[2], z[3]);
    *(float4*)(zp + 4) = make_float4(z[4], z[5], z[6], z[7]);
    *(float4*)(zp + 8) = make_float4(z[8], z[9], z[10], z[11]);
    *(float4*)(zp + 12) = make_float4(z[12], z[13], z[14], z[15]);
    float* mp = out + n64 + (size_t)i * 64 + wl * 16;
    *(float4*)mp = make_float4(v[0], v[1], v[2], v[3]);
    *(float4*)(mp + 4) = make_float4(v[4], v[5], v[6], v[7]);
    *(float4*)(mp + 8) = make_float4(v[8], v[9], v[10], v[11]);
    *(float4*)(mp + 12) = make_float4(v[12], v[13], v[14], v[15]);
  } else {
    float* lp = out + 2 * n64 + (size_t)i * 64 + (wl - 4) * 16;
    *(float4*)lp = make_float4(v[0], v[1], v[2], v[3]);
    *(float4*)(lp + 4) = make_float4(v[4], v[5], v[6], v[7]);
    *(float4*)(lp + 8) = make_float4(v[8], v[9], v[10], v[11]);
    *(float4*)(lp + 12) = make_float4(v[12], v[13], v[14], v[15]);
  }
}

}  // namespace

extern "C" void kernel_launch(void* const* d_in, const int* in_sizes, int n_in,
                              void* d_out, int out_size, void* d_ws, size_t ws_size,
                              hipStream_t stream) {
  const float* feature   = (const float*)d_in[0];
  const float* condition = (const float*)d_in[1];
  const int*   ei        = (const int*)d_in[2];
  const float* noise     = (const float*)d_in[3];
  const float* W_f2h     = (const float*)d_in[4];
  const float* b_f2h     = (const float*)d_in[5];
  const float* W_c2h     = (const float*)d_in[6];
  const float* b_c2h     = (const float*)d_in[7];
  const float* W_h2h     = (const float*)d_in[8];
  const float* b_h2h     = (const float*)d_in[9];
  const float* W_mean    = (const float*)d_in[10];
  const float* b_mean    = (const float*)d_in[11];
  const float* W_logvar  = (const float*)d_in[12];
  const float* b_logvar  = (const float*)d_in[13];

  const int* src = ei;
  const int* dst = ei + E;

  char* p = (char*)d_ws;
  auto alloc = [&](size_t bytes) {
    char* q = p;
    p += (bytes + 255) & ~(size_t)255;
    return q;
  };
  unsigned char*  buf192 = (unsigned char*)alloc((size_t)N * 192);       // [uf'|cond'] fp8
  unsigned char*  u2buf  = (unsigned char*)alloc((size_t)N * 128);       // u2' fp8
  unsigned char*  vbuf   = (unsigned char*)alloc((size_t)N * 128);       // v' fp8
  unsigned short* catbuf = (unsigned short*)alloc((size_t)N * 256 * 2);  // [f2h | c2h] bf16
  unsigned short* Pcbf   = (unsigned short*)alloc((size_t)N * 64 * 2);
  unsigned short* hbuf   = (unsigned short*)alloc((size_t)N * 128 * 2);  // h bf16
  int*   cnt     = (int*)alloc((size_t)N * 4);
  int*   cursor  = (int*)alloc((size_t)N * 4);
  int*   row_ptr = (int*)alloc((size_t)(N + 1) * 4);
  int*   csr_src = (int*)alloc((size_t)E * 4 + 1024);  // padded: edge-walk over-reads <=2 chunks
  int*   bsum    = (int*)alloc(256 * 4);
  float* dinv    = (float*)alloc((size_t)N * 4);
  unsigned short* Wf2h_p = (unsigned short*)alloc(4 * 512 * 8 * 2);
  unsigned short* Wc2h_p = (unsigned short*)alloc(2 * 512 * 8 * 2);
  unsigned short* Wh2h_p = (unsigned short*)alloc(8 * 512 * 8 * 2);
  unsigned short* Wcat_p = (unsigned short*)alloc(4 * 512 * 8 * 2);
  float* bcat    = (float*)alloc(128 * 4);
  (void)ws_size; (void)in_sizes; (void)n_in; (void)out_size;

  int nb = (N + 255) / 256;  // 196

  // CSR build + norm (XCD-local atomics; no serial scan kernel)
  zero_int<<<nb, 256, 0, stream>>>(cnt, N);
  count_xcd<<<1024, 256, 0, stream>>>(dst, cnt);
  block_sums<<<nb, 256, 0, stream>>>(cnt, bsum, N);
  scan_chunks2<<<nb, 256, 0, stream>>>(cnt, bsum, nb, row_ptr, cursor, dinv, N);
  scatter_xcd<<<1024, 256, 0, stream>>>(src, dst, cursor, csr_src);

  // conversions + weight packing
  cvt_cond<<<(N * 8 + 255) / 256, 256, 0, stream>>>(condition, dinv, buf192, N);
  pack_w<<<(4 * 512 + 255) / 256, 256, 0, stream>>>(W_f2h, 128, nullptr, 0, 128, 4, Wf2h_p);
  pack_w<<<(2 * 512 + 255) / 256, 256, 0, stream>>>(W_c2h, 128, nullptr, 0, 128, 2, Wc2h_p);
  pack_w<<<(8 * 512 + 255) / 256, 256, 0, stream>>>(W_h2h, 128, nullptr, 0, 128, 8, Wh2h_p);
  pack_w<<<(4 * 512 + 255) / 256, 256, 0, stream>>>(W_mean, 64, W_logvar, 64, 64, 4, Wcat_p);
  make_bcat<<<1, 128, 0, stream>>>(b_mean, b_logvar, bcat);

  int ggrid = (N + 127) / 128;  // 391

  // L1: uf' = dinv*(feature @ W_f2h) -> fp8 buf192 cols 0-127
  gemm_mfma<128, 2, true, 1><<<ggrid, 256, 0, stream>>>(feature, 128, Wf2h_p, dinv, buf192, 192, N);
  // fused prop over [uf'|cond'] fp8: f2h -> catbuf[:, :128], Pc -> Pcbf
  prop192<<<(N + 19) / 20, 256, 0, stream>>>(buf192, catbuf, Pcbf, row_ptr, csr_src, dinv, b_f2h, N);
  // c2h = tanh(Pc @ W_c2h + b) -> catbuf[:, 128:256]
  gemm_mfma<64, 1, false, 0><<<ggrid, 256, 0, stream>>>(Pcbf, 64, Wc2h_p, b_c2h, catbuf + 128, 256, N);
  // L2: u2' = dinv*(catbuf @ W_h2h) fp8 ; h = tanh(P(u2)+b) bf16 -> hbuf
  gemm_mfma<256, 2, false, 1><<<ggrid, 256, 0, stream>>>(catbuf, 256, Wh2h_p, dinv, u2buf, 128, N);
  prop128<<<(N + 31) / 32, 256, 0, stream>>>(u2buf, hbuf, row_ptr, csr_src, dinv, b_h2h, N);
  // L3: v' = dinv*(h @ [W_mean|W_logvar]) fp8 ; out = P(v)+bcat fused with reparam
  gemm_mfma<128, 2, false, 1><<<ggrid, 256, 0, stream>>>(hbuf, 128, Wcat_p, dinv, vbuf, 128, N);
  prop_fin<<<(N + 31) / 32, 256, 0, stream>>>(vbuf, row_ptr, csr_src, dinv, bcat, noise,
                                              (float*)d_out, N);
}